// Round 16
// baseline (1849.638 us; speedup 1.0000x reference)
//
#include <hip/hip_runtime.h>

// Two-layer tanh RNN, H=32, B=64, T=16384. Latency-bound sequential scan.
//
// Round-32: r-state affine fold — drop the tanh-final fma off the chain.
// R31 flat result killed the transport-occupancy model; surviving model:
// ~2 cyc/instr issue + ~165 cyc serial chain (exp2, rcp, dot tail, pack,
// first-transport latency). tanh h = 1 - 2*rcp(e+1) is AFFINE in
// r = rcp(e+1), and all consumers of h are linear: W.h = rowsum(W) - 2W.r.
// So the state IS r: chain ends at rcp -> pack immediately (3-dep tail).
// Folds (all at init): weights = -2*TSC*W (wave-B hi: -2*Wout); rowsums
// into seeds (binv, binvB) or output bias (bo2 = bo + rowsum(Wout));
// init r = (1-h)/2; h_final = 1-2r at epilogue.
// Transport (BCASTMIX 8 readlane + 8 uniform bperm), u-window, dot order,
// guards: byte-identical to green R31 (1836 us, absmax 3.906e-3).

#define T_LEN 16384
#define B_SZ  64
#define NW    (T_LEN / 32)   // 512 windows
#define TSC   2.885390082f   // 2*log2(e)

#if __has_builtin(__builtin_amdgcn_exp2f)
#define EXP2(x) __builtin_amdgcn_exp2f(x)
#else
#define EXP2(x) exp2f(x)
#endif

typedef _Float16 h2 __attribute__((ext_vector_type(2)));

__device__ __forceinline__ float rl(float v, int lane) {
  return __int_as_float(__builtin_amdgcn_readlane(__float_as_int(v), lane));
}

__device__ __forceinline__ h2 rl_h2(h2 v, int lane) {
  int o = __builtin_amdgcn_readlane(__builtin_bit_cast(int, v), lane);
  return __builtin_bit_cast(h2, o);
}

// Wave-uniform broadcast via the LDS crossbar (conflict-free mode): every
// lane pulls the pack register of lane (byteaddr>>2), byteaddr uniform.
__device__ __forceinline__ h2 bperm_h2(int byteaddr, h2 v) {
  int o = __builtin_amdgcn_ds_bpermute(byteaddr, __builtin_bit_cast(int, v));
  return __builtin_bit_cast(h2, o);
}

// quad_perm([1,0,3,2]): each lane sees its pair-neighbor's value.
__device__ __forceinline__ float pair_swap(float v) {
  int t = __builtin_amdgcn_update_dpp(0, __float_as_int(v), 0xB1, 0xF, 0xF, true);
  return __int_as_float(t);
}

// r-state update: r = rcp(2^v + 1). (h = 1 - 2r is never materialized in
// the loop; consumers have the affine folded into weights/seeds.)
__device__ __forceinline__ float rnext(float v) {
  float e = EXP2(v);
  return __builtin_amdgcn_rcpf(e + 1.f);
}

#if __has_builtin(__builtin_amdgcn_fdot2)
#define FDOT2(a, b, c) __builtin_amdgcn_fdot2((a), (b), (c), false)
#else
#define FDOT2(a, b, c) \
  fmaf((float)(a).x, (float)(b).x, fmaf((float)(a).y, (float)(b).y, (c)))
#endif

// Pack this lane's state with its pair-neighbor: even lane 2j ends with
// (r[2j], r[2j+1]). DPP on f32 first, then ONE packed convert (RTZ).
__device__ __forceinline__ h2 pack_state(float rcur) {
  float rsw = pair_swap(rcur);
#if __has_builtin(__builtin_amdgcn_cvt_pkrtz)
  return __builtin_bit_cast(h2, __builtin_amdgcn_cvt_pkrtz(rcur, rsw));
#else
  h2 p; p.x = (_Float16)rcur; p.y = (_Float16)rsw; return p;
#endif
}

// Dual-pipe broadcast: pair j (source lane 2j). j=0..7 via readlane
// (VALU), j=8..15 via uniform bpermute (DS), interleaved.
#define BCASTMIX(dst, src_pk)                                  \
  _Pragma("unroll")                                            \
  for (int j_ = 0; j_ < 8; ++j_) {                             \
    (dst)[j_]     = rl_h2((src_pk), 2 * j_);                   \
    (dst)[j_ + 8] = bperm_h2(64 + 8 * j_, (src_pk));           \
  }

// 32-term dot via 16 dot2, 4 accumulators (depth 4) + 2-level tree.
__device__ __forceinline__ float dot32h(const h2* w, const h2* hb, float seed) {
  float a0 = seed, a1 = 0.f, a2 = 0.f, a3 = 0.f;
#pragma unroll
  for (int j = 0; j < 4; ++j) {
    a0 = FDOT2(w[4 * j + 0], hb[4 * j + 0], a0);
    a1 = FDOT2(w[4 * j + 1], hb[4 * j + 1], a1);
    a2 = FDOT2(w[4 * j + 2], hb[4 * j + 2], a2);
    a3 = FDOT2(w[4 * j + 3], hb[4 * j + 3], a3);
  }
  return (a0 + a1) + (a2 + a3);
}

__global__ __launch_bounds__(128, 1) void rnn2_kernel(
    const float* __restrict__ x,    const float* __restrict__ hs,
    const float* __restrict__ Wih0, const float* __restrict__ Whh0,
    const float* __restrict__ bih0, const float* __restrict__ bhh0,
    const float* __restrict__ Wih1, const float* __restrict__ Whh1,
    const float* __restrict__ bih1, const float* __restrict__ bhh1,
    const float* __restrict__ Wout, const float* __restrict__ bout,
    float* __restrict__ out)
{
  __shared__ __align__(16) float uwin[2][1024];   // A->B; slot t2*32 + row
  __shared__ __align__(16) float scratch[1024];   // sink for lo-lane publishes

  const int  tid = (int)threadIdx.x;
  const int  wv  = tid >> 6;            // 0 = wave A (h0), 1 = wave B (h1)
  const int  m   = tid & 63;
  const int  r   = m & 31;              // row owned by this lane
  const bool hi  = (m >= 32);           // secondary-matrix half
  const int  b   = (int)blockIdx.x;

  // Per-lane full 32-float row, packed to 16 f16 pairs, affine-folded:
  //  A lo: w=-2*TSC*Whh0[r];  A hi: w=-2*TSC*Wih1[r]
  //  B lo: w=-2*TSC*Whh1[r];  B hi: w=-2*Wout (raw scale; feeds out)
  // rowsum(W) terms go to binv (A), binvB (B lo), bo2 (B hi).
  const float* pw = (wv == 0) ? (hi ? (Wih1 + r * 32) : (Whh0 + r * 32))
                              : (hi ? Wout : (Whh1 + r * 32));
  const float wsc = (wv == 1 && hi) ? -2.f : (-2.f * TSC);
  h2 w[16];
  float rsum = 0.f;                     // raw rowsum of pw
#pragma unroll
  for (int k = 0; k < 8; ++k) {
    float4 q = ((const float4*)pw)[k];
    rsum += (q.x + q.y) + (q.z + q.w);
    w[2 * k].x     = (_Float16)(q.x * wsc);
    w[2 * k].y     = (_Float16)(q.y * wsc);
    w[2 * k + 1].x = (_Float16)(q.z * wsc);
    w[2 * k + 1].y = (_Float16)(q.w * wsc);
  }

  float xw = 0.f, binv = 0.f, binvB = 0.f;
  float bo2 = bout[0];
  if (wv == 0) {
    if (hi) binv = TSC * (bih1[r] + bhh1[r] + rsum);     // u seed + rowsum
    else  { binv = TSC * (bih0[r] + bhh0[r] + rsum); xw = TSC * Wih0[r]; }
  } else {
    if (hi) bo2 += rsum;                                 // out bias + rowsum
    else    binvB = TSC * rsum;                          // Whh1 rowsum term
  }

  // State register: lane k (k<32) holds r[k] = (1 - h[k])/2 in f32.
  // Hi lanes carry garbage copies; pack/BCASTMIX read even lanes 0..30.
  float hsv  = (wv == 0) ? hs[b * 32 + r] : hs[2048 + b * 32 + r];
  float rcur = fmaf(-0.5f, hsv, 0.5f);

  // Wave A publish pointers: hi lanes -> uwin row r, lo lanes -> scratch.
  float* up0 = hi ? &uwin[0][r] : &scratch[r];
  float* up1 = hi ? &uwin[1][r] : &scratch[r];

  const float* xb   = x + (size_t)b * T_LEN;
  float*       outp = out + (size_t)b * T_LEN;       // outs[b*T + t]
  float*       hf   = out + (size_t)B_SZ * T_LEN;    // h_final [2,B,H]

  float obuf = 0.f;
  float xcur = 0.f;
  if (wv == 0) xcur = xb[m];            // window 0 chunk (lanes 0..31 used)

  for (int wdx = 0; wdx <= NW; ++wdx) {
    if (wv == 0) {
      if (wdx < NW) {
        // Prefetch next window's x chunk; consumed 32 steps from now.
        float xnext = 0.f;
        if (wdx + 1 < NW) {
          int xi = 32 * (wdx + 1) + m; if (xi > T_LEN - 1) xi = T_LEN - 1;
          xnext = xb[xi];
        }
        float* up = (wdx & 1) ? up1 : up0;
#pragma unroll 8
        for (int t2 = 0; t2 < 32; ++t2) {
          h2 hpk = pack_state(rcur);        // r0(t-1) packed pairs
          h2 hb[16];
          BCASTMIX(hb, hpk);                // 8 readlane + 8 bperm
          float xv   = rl(xcur, t2);        // x(t)   (off-chain)
          float seed = fmaf(xv, xw, binv);  // lo: TSC*(xW+b0+rs); hi: TSC*(b1+rs)
          float acc  = dot32h(w, hb, seed); // lo: tanh arg v; hi: TSC*u(t-1)
          up[t2 * 32] = acc;                // hi publishes u; lo -> scratch
          rcur = rnext(acc);                // lo lanes: r0(t) — chain ends at rcp
        }
        xcur = xnext;
      }
    } else {
      if (wdx >= 1) {
        const int wb = wdx - 1;             // steps t = 32*wb-1 .. 32*wb+30
        const float* ub = &uwin[wb & 1][r];
        float uval = ub[0];                 // TSC*u(32*wb-1)
#pragma unroll 8
        for (int t2 = 0; t2 < 32; ++t2) {
          const int t = 32 * wb - 1 + t2;
          h2 hpk = pack_state(rcur);        // r1(t-1) packed pairs
          h2 hb[16];
          BCASTMIX(hb, hpk);                // 8 readlane + 8 bperm
          float sB  = (hi ? 0.f : uval) + binvB;   // u + rowsum term; hi: 0
          float acc = dot32h(w, hb, sB);    // lo: tanh arg; hi: out(t-1)-bo2
          float unext = ub[((t2 + 1) & 31) * 32];  // pipelined u-read
          float r1n = rnext(acc);
          obuf = (m == 32 + t2) ? acc : obuf;      // hi lane t2: out(t-1)-bo2
          if (t >= 0) rcur = r1n;           // uniform guard (skips wb=0,t2=0)
          uval = unext;
        }
        const int idx = 32 * wb - 2 + r;    // hi lane 32+k holds out(32wb-2+k)
        if (hi && idx >= 0) outp[idx] = obuf + bo2;  // coalesced store
      }
    }
    __syncthreads();   // window handoff (uwin parity swap)
  }

  // Epilogue 1 (wave A): publish TSC*u(T-1) from r0(T-1); h_final L0.
  if (wv == 0) {
    h2 hpk = pack_state(rcur);              // r0(T-1)
    h2 hb[16];
    BCASTMIX(hb, hpk);
    float acc = dot32h(w, hb, binv);        // hi: TSC*(b1 + Wih1.h0(T-1))
    if (hi) uwin[0][r] = acc;
    else    hf[b * 32 + r] = fmaf(-2.f, rcur, 1.f);  // h_final L0 = 1-2r
  }
  __syncthreads();

  // Epilogue 2 (wave B): h1(T-1), out(T-2), out(T-1), h_final L1.
  if (wv == 1) {
    float uT = uwin[0][r];                  // TSC*u(T-1)
    h2 hpk = pack_state(rcur);              // r1(T-2)
    h2 hb[16];
    BCASTMIX(hb, hpk);
    float acc = dot32h(w, hb, (hi ? 0.f : uT) + binvB);
    if (m == 32) outp[T_LEN - 2] = acc + bo2;     // out(T-2)
    float r1T = rnext(acc);                 // r1(T-1), valid in lo lanes
    h2 hpk2 = pack_state(r1T);
    h2 hb2[16];
    BCASTMIX(hb2, hpk2);
    float acc2 = dot32h(w, hb2, binvB * 0.f + (hi ? 0.f : 0.f)); // seed 0
    if (m == 32) outp[T_LEN - 1] = acc2 + bo2;    // out(T-1)
    if (!hi) hf[2048 + b * 32 + r] = fmaf(-2.f, r1T, 1.f);  // h_final L1
  }
}

extern "C" void kernel_launch(void* const* d_in, const int* in_sizes, int n_in,
                              void* d_out, int out_size, void* d_ws, size_t ws_size,
                              hipStream_t stream) {
  rnn2_kernel<<<dim3(B_SZ), dim3(128), 0, stream>>>(
      (const float*)d_in[0],  (const float*)d_in[1],  (const float*)d_in[2],
      (const float*)d_in[3],  (const float*)d_in[4],  (const float*)d_in[5],
      (const float*)d_in[6],  (const float*)d_in[7],  (const float*)d_in[8],
      (const float*)d_in[9],  (const float*)d_in[10], (const float*)d_in[11],
      (float*)d_out);
}